// Round 19
// baseline (171.640 us; speedup 1.0000x reference)
//
#include <hip/hip_runtime.h>
#include <cstdint>

#define NENT 100000
#define EPS 1e-5f

// ---- ws layout (float offsets) ----
constexpr long REL_A    = 0;        // 2500
constexpr long REL_B    = 2500;     // 2500
constexpr long EPART    = 5000;     // 32 (16 blocks x {sum, sumsq})
constexpr long EAB      = 5040;     // 2 (a0, c0 finalized)
constexpr long A1O      = 5056;     // 100
constexpr long C1O      = 5156;     // 100
constexpr long PART_OFF = 5888;     // 409600: bn1part [200][1024] early, then part [4][100][1024]
constexpr long XBUF_OFF = 415488;   // 1024*3600  = 3686400  (hosts rel-stat partials [250][5000] BEFORE conv)
constexpr long XHAT_OFF = 4101888;  // 1024*128 bf16 = 65536 floats
constexpr long PSTAT    = XBUF_OFF; // 1250000 floats, dead once k_stats2 completes

typedef __attribute__((ext_vector_type(8))) __bf16 bf16x8;
typedef __attribute__((ext_vector_type(4))) float  f32x4;

#define BARLK() asm volatile("s_waitcnt lgkmcnt(0)\n\ts_barrier" ::: "memory")

__device__ __forceinline__ unsigned short f2bf(float f) {
    unsigned int u = __float_as_uint(f);
    unsigned int r = (u + 0x7FFFu + ((u >> 16) & 1u)) >> 16;
    return (unsigned short)r;
}

// K1a: blocks 0..249  -> rel-stat partials (2 rows/block, float4-streamed) -> [250][5000]
//      blocks 250..265 -> e-BN0 partial sums
__global__ void k_stats1(const int* __restrict__ rel, const float* __restrict__ emb_rel,
                         const int* __restrict__ e1, const float* __restrict__ emb_e,
                         float* __restrict__ ws) {
    __shared__ float shmem[512];
    int tid = threadIdx.x, blk = blockIdx.x;
    if (blk < 250) {
        int* cnti = (int*)shmem;
        for (int i = tid; i < 512; i += 256) cnti[i] = 0;
        __syncthreads();
        for (int i = tid; i < 1024; i += 256) atomicAdd(&cnti[rel[i]], 1);
        __syncthreads();
        f32x4 s4[3], q4[3];
#pragma unroll
        for (int k = 0; k < 3; k++) { s4[k] = f32x4{0.f,0.f,0.f,0.f}; q4[k] = f32x4{0.f,0.f,0.f,0.f}; }
#pragma unroll
        for (int rr = 0; rr < 2; rr++) {
            int r = blk * 2 + rr;
            float c = (float)cnti[r];
            if (c != 0.f) {
                const f32x4* row4 = (const f32x4*)(emb_rel + (long)r * 2500);  // 625 float4
#pragma unroll
                for (int k = 0; k < 3; k++) {
                    int idx = tid + k * 256;
                    if (idx < 625) {
                        f32x4 v = row4[idx];
#pragma unroll
                        for (int cc = 0; cc < 4; cc++) {
                            s4[k][cc] = fmaf(c, v[cc], s4[k][cc]);
                            q4[k][cc] = fmaf(c * v[cc], v[cc], q4[k][cc]);
                        }
                    }
                }
            }
        }
        float* ps = ws + PSTAT + (long)blk * 5000;
#pragma unroll
        for (int k = 0; k < 3; k++) {
            int idx = tid + k * 256;
            if (idx < 625) {
                *(f32x4*)(ps + idx * 4)        = s4[k];
                *(f32x4*)(ps + 2500 + idx * 4) = q4[k];
            }
        }
    } else if (blk < 266) {
        float* ps = shmem;
        __shared__ float pq[256];
        __shared__ int eidx[64];
        int bi = blk - 250;
        if (tid < 64) eidx[tid] = e1[bi * 64 + tid];
        __syncthreads();
        float s = 0.f, q = 0.f;
        for (int i = tid; i < 6400; i += 256) {
            int b = i / 100, d = i - b * 100;
            float v = emb_e[(long)eidx[b] * 100 + d];
            s += v; q += v * v;
        }
        ps[tid] = s; pq[tid] = q;
        __syncthreads();
        for (int off = 128; off > 0; off >>= 1) {
            if (tid < off) { ps[tid] += ps[tid + off]; pq[tid] += pq[tid + off]; }
            __syncthreads();
        }
        if (tid == 0) { ws[EPART + bi * 2] = ps[0]; ws[EPART + bi * 2 + 1] = pq[0]; }
    }
}

// K1b (512 thr): blocks 0..39 -> reduce [250][5000] partials -> REL_A/REL_B; block 40 -> EAB
__global__ void k_stats2(const float* __restrict__ grel, const float* __restrict__ brel,
                         const float* __restrict__ g0, const float* __restrict__ b0,
                         float* __restrict__ ws) {
    __shared__ float ps[512], pq[512];
    int tid = threadIdx.x, blk = blockIdx.x;
    if (blk < 40) {
        int f = blk * 64 + (tid & 63);
        int g = tid >> 6;   // 8 row-groups
        float s = 0.f, q = 0.f;
        for (int p = g; p < 250; p += 8) {
            s += ws[PSTAT + (long)p * 5000 + f];
            q += ws[PSTAT + (long)p * 5000 + 2500 + f];
        }
        ps[tid] = s; pq[tid] = q;
        __syncthreads();
        if (tid < 64) {
            float ss = 0.f, qq = 0.f;
#pragma unroll
            for (int k = 0; k < 8; k++) { ss += ps[tid + k * 64]; qq += pq[tid + k * 64]; }
            float mean = ss * (1.f / 1024.f);
            float var  = qq * (1.f / 1024.f) - mean * mean;
            float a = grel[f] * rsqrtf(var + EPS);
            ws[REL_A + f] = a;
            ws[REL_B + f] = brel[f] - mean * a;
        }
    } else if (tid == 0) {
        float s = 0.f, q = 0.f;
#pragma unroll
        for (int i = 0; i < 16; i++) { s += ws[EPART + 2 * i]; q += ws[EPART + 2 * i + 1]; }
        float mean = s * (1.f / 102400.f);
        float var  = q * (1.f / 102400.f) - mean * mean;
        float a = g0[0] * rsqrtf(var + EPS);
        ws[EAB]     = a;
        ws[EAB + 1] = b0[0] - mean * a;
    }
}

// K2: per-sample grouped conv; emits BN1 partials TRANSPOSED: bn1part[f][b] / [100+f][b]
__global__ void k_conv(const int* __restrict__ e1, const int* __restrict__ rel,
                       const float* __restrict__ emb_e, const float* __restrict__ emb_rel,
                       const float* __restrict__ ws, float* __restrict__ xout,
                       float* __restrict__ bn1part) {
    __shared__ float es[100];
    __shared__ float flt[2500];
    __shared__ float prs[600], prq[600];
    int b = blockIdx.x, tid = threadIdx.x;
    float a0 = ws[EAB], c0 = ws[EAB + 1];
    long ebase = (long)e1[b] * 100;
    for (int i = tid; i < 100; i += 256) es[i] = a0 * emb_e[ebase + i] + c0;
    long rbase = (long)rel[b] * 2500;
    for (int i = tid; i < 2500; i += 256) flt[i] = ws[REL_A + i] * emb_rel[rbase + i] + ws[REL_B + i];
    __syncthreads();
    for (int u = tid; u < 600; u += 256) {
        int f = u / 6, oi = u - f * 6;
        float er[5][10];
#pragma unroll
        for (int p = 0; p < 5; p++)
#pragma unroll
            for (int c = 0; c < 10; c++) er[p][c] = es[(oi + p) * 10 + c];
        float fw[25];
#pragma unroll
        for (int k = 0; k < 25; k++) fw[k] = flt[f * 25 + k];
        float* dst = xout + (long)b * 3600 + f * 36 + oi * 6;
        float s6 = 0.f, q6 = 0.f;
#pragma unroll
        for (int oj = 0; oj < 6; oj++) {
            float acc = 0.f;
#pragma unroll
            for (int p = 0; p < 5; p++)
#pragma unroll
                for (int q = 0; q < 5; q++) acc += er[p][oj + q] * fw[p * 5 + q];
            dst[oj] = acc;
            s6 += acc; q6 = fmaf(acc, acc, q6);
        }
        prs[u] = s6; prq[u] = q6;
    }
    __syncthreads();
    if (tid < 100) {
        float s = 0.f, q = 0.f;
#pragma unroll
        for (int k = 0; k < 6; k++) { s += prs[tid * 6 + k]; q += prq[tid * 6 + k]; }
        bn1part[(long)tid * 1024 + b]         = s;
        bn1part[(long)(100 + tid) * 1024 + b] = q;
    }
}

// K3: reduce BN1 partials (COALESCED rows) -> a1s/c1s
__global__ void k_bn1r(const float* __restrict__ bn1part, const float* __restrict__ g1,
                       const float* __restrict__ b1, float* __restrict__ ws) {
    __shared__ float ps[256], pq[256];
    int f = blockIdx.x, tid = threadIdx.x;
    float s = 0.f, q = 0.f;
    for (int b = tid; b < 1024; b += 256) {
        s += bn1part[(long)f * 1024 + b];
        q += bn1part[(long)(100 + f) * 1024 + b];
    }
    ps[tid] = s; pq[tid] = q;
    __syncthreads();
    for (int off = 128; off > 0; off >>= 1) {
        if (tid < off) { ps[tid] += ps[tid + off]; pq[tid] += pq[tid + off]; }
        __syncthreads();
    }
    if (tid == 0) {
        float mean = ps[0] * (1.f / 36864.f);
        float var  = pq[0] * (1.f / 36864.f) - mean * mean;
        float a = g1[f] * rsqrtf(var + EPS);
        ws[A1O + f] = a;
        ws[C1O + f] = b1[f] - mean * a;
    }
}

// K4: FC partials (round-17 form — best measured 37.5 µs). grid (256, 4):
// 4 samples x 900-k chunk; j-outer t-loop with break; xs reads broadcast.
// part[(kc*100+j)*1024 + b]
__global__ void __launch_bounds__(256, 4)
k_fc(const float* __restrict__ xbuf, const float* __restrict__ fc_w,
     const float* __restrict__ ws, float* __restrict__ part) {
    __shared__ float a1s[100], c1s[100];
    __shared__ float xs[4][900];
    int tid = threadIdx.x;
    int sb = blockIdx.x, kc = blockIdx.y;
    if (tid < 100) { a1s[tid] = ws[A1O + tid]; c1s[tid] = ws[C1O + tid]; }
    __syncthreads();
    int b0s = sb * 4, k0 = kc * 900;
    for (int idx = tid; idx < 3600; idx += 256) {
        int s = idx / 900, k = idx - s * 900;
        int kg = k0 + k;
        int f = kg / 36;
        float v = xbuf[(long)(b0s + s) * 3600 + kg];
        v = a1s[f] * v + c1s[f];
        xs[s][k] = v > 0.f ? v : 0.f;
    }
    __syncthreads();
    int w = tid >> 6, l = tid & 63;
    int g = l >> 4, ks16 = l & 15;      // j-sub within group / k-lane
    for (int t = 0; t < 7; t++) {
        int grp = w + 4 * t;            // wave-uniform
        if (grp >= 25) break;
        int j = grp * 4 + g;
        const float* wrow = fc_w + (long)j * 3600 + k0;
        float acc[4];
#pragma unroll
        for (int s = 0; s < 4; s++) acc[s] = 0.f;
#pragma unroll
        for (int i = 0; i < 15; i++) {
            int kk = ks16 + i * 16;     // float4 index, 225 total
            if (kk < 225) {
                float4 w4 = *(const float4*)(wrow + kk * 4);
#pragma unroll
                for (int s = 0; s < 4; s++) {
                    float4 x4 = *(const float4*)(&xs[s][kk * 4]);
                    acc[s] += w4.x * x4.x + w4.y * x4.y + w4.z * x4.z + w4.w * x4.w;
                }
            }
        }
#pragma unroll
        for (int s = 0; s < 4; s++) {
            float v = acc[s];
            v += __shfl_xor(v, 1);
            v += __shfl_xor(v, 2);
            v += __shfl_xor(v, 4);
            v += __shfl_xor(v, 8);
            acc[s] = v;
        }
#pragma unroll
        for (int s = 0; s < 4; s++) {
            if (ks16 == s)
                part[((long)kc * 100 + j) * 1024 + b0s + s] = acc[s];
        }
    }
}

// K5: combine FC partials + fc_b, BN2 stats + apply + ReLU -> xhat bf16 [1024][128]
__global__ void k_bn2x(const float* __restrict__ part, const float* __restrict__ fc_b,
                       const float* __restrict__ g2, const float* __restrict__ b2,
                       unsigned short* __restrict__ xhat) {
    int j = blockIdx.x, tid = threadIdx.x;
    if (j >= 100) {
        for (int t = 0; t < 4; t++) xhat[(long)(tid + t * 256) * 128 + j] = 0;
        return;
    }
    __shared__ float ps[256], pq[256];
    __shared__ float ab[2];
    float v[4];
    float s = 0.f, q = 0.f;
#pragma unroll
    for (int t = 0; t < 4; t++) {
        int b = tid + t * 256;
        float x = part[(long)j * 1024 + b] + part[(long)(100 + j) * 1024 + b]
                + part[(long)(200 + j) * 1024 + b] + part[(long)(300 + j) * 1024 + b]
                + fc_b[j];
        v[t] = x; s += x; q += x * x;
    }
    ps[tid] = s; pq[tid] = q;
    __syncthreads();
    for (int off = 128; off > 0; off >>= 1) {
        if (tid < off) { ps[tid] += ps[tid + off]; pq[tid] += pq[tid + off]; }
        __syncthreads();
    }
    if (tid == 0) {
        float mean = ps[0] * (1.f / 1024.f);
        float var  = pq[0] * (1.f / 1024.f) - mean * mean;
        float a = g2[j] * rsqrtf(var + EPS);
        ab[0] = a; ab[1] = b2[j] - mean * a;
    }
    __syncthreads();
    float a = ab[0], c = ab[1];
#pragma unroll
    for (int t = 0; t < 4; t++) {
        float x = a * v[t] + c;
        x = x > 0.f ? x : 0.f;
        xhat[(long)(tid + t * 256) * 128 + j] = f2bf(x);
    }
}

// K6: logits GEMM (r16): N-tile 256, 2 blocks/CU, 1 KB contiguous NT row stores,
// chunked bijective XCD swizzle (nwg=391: q=48,r=7).
__global__ void __launch_bounds__(256, 2)
k_gemm(const unsigned short* __restrict__ xhat, const float* __restrict__ emb_e,
       const float* __restrict__ bias, float* __restrict__ out) {
    __shared__ __align__(16) unsigned short Es[256 * 128];  // 64 KB
    char* EsB = (char*)Es;
    int tid = threadIdx.x;
    int b0i = blockIdx.x;
    int xcd = b0i & 7, rnd = b0i >> 3;
    int nblk = (xcd < 7 ? xcd * 49 : 343) + rnd;
    int n0 = nblk * 256;

    {
        int r = tid;
        int g = n0 + r;
        unsigned int rowb = (unsigned)r * 256u;
        unsigned int sw = ((unsigned)r & 7u) << 4;
        ushort4 z; z.x = z.y = z.z = z.w = 0;
        if (g < NENT) {
            const float4* src = (const float4*)(emb_e + (long)g * 100);
#pragma unroll
            for (int i = 0; i < 25; i++) {
                float4 v = src[i];
                ushort4 h;
                h.x = f2bf(v.x); h.y = f2bf(v.y); h.z = f2bf(v.z); h.w = f2bf(v.w);
                *(ushort4*)(EsB + ((rowb + 8u * i) ^ sw)) = h;
            }
        } else {
#pragma unroll
            for (int i = 0; i < 25; i++) *(ushort4*)(EsB + ((rowb + 8u * i) ^ sw)) = z;
        }
#pragma unroll
        for (int zz = 0; zz < 7; zz++) *(ushort4*)(EsB + ((rowb + 200u + 8u * zz) ^ sw)) = z;
    }
    __syncthreads();

    int w = tid >> 6, l = tid & 63;
    int l15 = l & 15, l4 = l >> 4;

    bf16x8 Af[4][4];   // [ks][fe]
#pragma unroll
    for (int fe = 0; fe < 4; fe++) {
        unsigned int r = (unsigned)(w * 64 + fe * 16 + l15);
        unsigned int base = r * 256u + (unsigned)(l4 * 16);
        unsigned int sw = (r & 7u) << 4;
#pragma unroll
        for (int ks = 0; ks < 4; ks++)
            Af[ks][fe] = *(const bf16x8*)(EsB + ((base + (unsigned)(ks * 64)) ^ sw));
    }
    BARLK();   // Es dead as bf16 tile; reuse as float[64][256]

    int colg = n0 + l * 4;
    bool colv = colg < NENT;
    f32x4 bb = colv ? *(const f32x4*)(bias + colg) : f32x4{0.f, 0.f, 0.f, 0.f};

    int xrow = l15 * 128 + l4 * 8;

    bf16x8 Bp[4];
#pragma unroll
    for (int fx = 0; fx < 4; fx++)
        Bp[fx] = *(const bf16x8*)(xhat + (long)(fx * 2048 + xrow));

    for (int chunk = 0; chunk < 16; ++chunk) {
        int m0 = chunk * 64;
        f32x4 acc[4][4];
#pragma unroll
        for (int fe = 0; fe < 4; fe++)
#pragma unroll
            for (int fx = 0; fx < 4; fx++) acc[fe][fx] = f32x4{0.f, 0.f, 0.f, 0.f};

#pragma unroll
        for (int fe = 0; fe < 4; fe++)
#pragma unroll
            for (int fx = 0; fx < 4; fx++)
                acc[fe][fx] = __builtin_amdgcn_mfma_f32_16x16x32_bf16(Af[0][fe], Bp[fx], acc[fe][fx], 0, 0, 0);

#pragma unroll
        for (int ks = 1; ks < 4; ++ks) {
            bf16x8 Bf[4];
#pragma unroll
            for (int fx = 0; fx < 4; fx++)
                Bf[fx] = *(const bf16x8*)(xhat + (long)(m0 * 128 + fx * 2048 + ks * 32 + xrow));
#pragma unroll
            for (int fe = 0; fe < 4; fe++)
#pragma unroll
                for (int fx = 0; fx < 4; fx++)
                    acc[fe][fx] = __builtin_amdgcn_mfma_f32_16x16x32_bf16(Af[ks][fe], Bf[fx], acc[fe][fx], 0, 0, 0);
        }

        if (chunk < 15) {
            int m0n = (chunk + 1) * 64;
#pragma unroll
            for (int fx = 0; fx < 4; fx++)
                Bp[fx] = *(const bf16x8*)(xhat + (long)(m0n * 128 + fx * 2048 + xrow));
        }

#pragma unroll
        for (int fe = 0; fe < 4; fe++) {
            unsigned int s = (unsigned)(w * 16 + fe * 4 + l4);
#pragma unroll
            for (int fx = 0; fx < 4; fx++) {
                unsigned int row = (unsigned)(fx * 16 + l15);
                *(f32x4*)(EsB + row * 1024u + ((s ^ (row & 7u)) * 16u)) = acc[fe][fx];
            }
        }
        BARLK();

#pragma unroll
        for (int pass = 0; pass < 16; pass++) {
            unsigned int row = (unsigned)(pass * 4 + w);
            f32x4 v = *(f32x4*)(EsB + row * 1024u + ((((unsigned)l) ^ (row & 7u)) * 16u));
            f32x4 o;
#pragma unroll
            for (int k = 0; k < 4; k++) {
                float x = v[k] + bb[k];
                float e = __builtin_amdgcn_exp2f(x * -1.44269504f);
                o[k] = __builtin_amdgcn_rcpf(1.0f + e);
            }
            if (colv)
                __builtin_nontemporal_store(o, (f32x4*)(out + (long)(m0 + row) * NENT + colg));
        }
        BARLK();
    }
}

extern "C" void kernel_launch(void* const* d_in, const int* in_sizes, int n_in,
                              void* d_out, int out_size, void* d_ws, size_t ws_size,
                              hipStream_t stream) {
    const int*   e1      = (const int*)d_in[0];
    const int*   rel     = (const int*)d_in[1];
    const float* emb_e   = (const float*)d_in[2];
    const float* emb_rel = (const float*)d_in[3];
    const float* fc_w    = (const float*)d_in[4];
    const float* fc_b    = (const float*)d_in[5];
    const float* bias    = (const float*)d_in[6];
    const float* g0      = (const float*)d_in[7];
    const float* b0      = (const float*)d_in[8];
    const float* g1      = (const float*)d_in[9];
    const float* b1      = (const float*)d_in[10];
    const float* grel    = (const float*)d_in[11];
    const float* brel    = (const float*)d_in[12];
    const float* g2      = (const float*)d_in[13];
    const float* b2      = (const float*)d_in[14];
    float* ws  = (float*)d_ws;
    float* out = (float*)d_out;

    hipLaunchKernelGGL(k_stats1, dim3(266), dim3(256), 0, stream, rel, emb_rel, e1, emb_e, ws);
    hipLaunchKernelGGL(k_stats2, dim3(41), dim3(512), 0, stream, grel, brel, g0, b0, ws);
    hipLaunchKernelGGL(k_conv, dim3(1024), dim3(256), 0, stream, e1, rel, emb_e, emb_rel,
                       ws, ws + XBUF_OFF, ws + PART_OFF);
    hipLaunchKernelGGL(k_bn1r, dim3(100), dim3(256), 0, stream, ws + PART_OFF, g1, b1, ws);
    hipLaunchKernelGGL(k_fc, dim3(256, 4), dim3(256), 0, stream, ws + XBUF_OFF, fc_w, ws, ws + PART_OFF);
    hipLaunchKernelGGL(k_bn2x, dim3(128), dim3(256), 0, stream, ws + PART_OFF, fc_b, g2, b2,
                       (unsigned short*)(ws + XHAT_OFF));
    hipLaunchKernelGGL(k_gemm, dim3(391), dim3(256), 0, stream,
                       (const unsigned short*)(ws + XHAT_OFF), emb_e, bias, out);
}

// Round 21
// 162.660 us; speedup vs baseline: 1.0552x; 1.0552x over previous
//
#include <hip/hip_runtime.h>
#include <cstdint>

#define NENT 100000
#define EPS 1e-5f

// ---- ws layout (float offsets) ----
constexpr long REL_A    = 0;        // 2500
constexpr long REL_B    = 2500;     // 2500
constexpr long EPART    = 5000;     // 32 (16 blocks x {sum, sumsq})
constexpr long EAB      = 5040;     // 2 (a0, c0 finalized)
constexpr long A1O      = 5056;     // 100
constexpr long C1O      = 5156;     // 100
constexpr long PART_OFF = 5888;     // 409600: bn1part [200][1024] early, then part [4][100][1024]
constexpr long XBUF_OFF = 415488;   // 1024*3600  = 3686400  (hosts rel-stat partials [125][5000] BEFORE conv)
constexpr long XHAT_OFF = 4101888;  // 1024*128 bf16 = 65536 floats
constexpr long PSTAT    = XBUF_OFF; // 625000 floats, dead once k_stats2 completes

typedef __attribute__((ext_vector_type(8))) __bf16 bf16x8;
typedef __attribute__((ext_vector_type(4))) float  f32x4;

#define BARLK() asm volatile("s_waitcnt lgkmcnt(0)\n\ts_barrier" ::: "memory")

__device__ __forceinline__ unsigned short f2bf(float f) {
    unsigned int u = __float_as_uint(f);
    unsigned int r = (u + 0x7FFFu + ((u >> 16) & 1u)) >> 16;
    return (unsigned short)r;
}

// K1a: blocks 0..124  -> rel-stat partials (4 rows/block, coalesced) -> [125][5000]
//      blocks 125..140 -> e-BN0 partial sums
__global__ void k_stats1(const int* __restrict__ rel, const float* __restrict__ emb_rel,
                         const int* __restrict__ e1, const float* __restrict__ emb_e,
                         float* __restrict__ ws) {
    __shared__ float shmem[512];
    int tid = threadIdx.x, blk = blockIdx.x;
    if (blk < 125) {
        int* cnti = (int*)shmem;
        for (int i = tid; i < 512; i += 256) cnti[i] = 0;
        __syncthreads();
        for (int i = tid; i < 1024; i += 256) atomicAdd(&cnti[rel[i]], 1);
        __syncthreads();
        float s[10], q[10];
#pragma unroll
        for (int k = 0; k < 10; k++) { s[k] = 0.f; q[k] = 0.f; }
#pragma unroll
        for (int rr = 0; rr < 4; rr++) {
            int r = blk * 4 + rr;
            float c = (float)cnti[r];
            if (c != 0.f) {
                const float* row = emb_rel + (long)r * 2500;
#pragma unroll
                for (int k = 0; k < 10; k++) {
                    int idx = tid + k * 256;
                    if (idx < 2500) {
                        float v = row[idx];
                        s[k] = fmaf(c, v, s[k]);
                        q[k] = fmaf(c * v, v, q[k]);
                    }
                }
            }
        }
        float* ps = ws + PSTAT + (long)blk * 5000;
#pragma unroll
        for (int k = 0; k < 10; k++) {
            int idx = tid + k * 256;
            if (idx < 2500) { ps[idx] = s[k]; ps[2500 + idx] = q[k]; }
        }
    } else if (blk < 141) {
        float* ps = shmem;
        __shared__ float pq[256];
        __shared__ int eidx[64];
        int bi = blk - 125;
        if (tid < 64) eidx[tid] = e1[bi * 64 + tid];
        __syncthreads();
        float s = 0.f, q = 0.f;
        for (int i = tid; i < 6400; i += 256) {
            int b = i / 100, d = i - b * 100;
            float v = emb_e[(long)eidx[b] * 100 + d];
            s += v; q += v * v;
        }
        ps[tid] = s; pq[tid] = q;
        __syncthreads();
        for (int off = 128; off > 0; off >>= 1) {
            if (tid < off) { ps[tid] += ps[tid + off]; pq[tid] += pq[tid + off]; }
            __syncthreads();
        }
        if (tid == 0) { ws[EPART + bi * 2] = ps[0]; ws[EPART + bi * 2 + 1] = pq[0]; }
    }
}

// K1b (512 thr): blocks 0..39 -> reduce partials -> REL_A/REL_B; block 40 -> EAB
__global__ void k_stats2(const float* __restrict__ grel, const float* __restrict__ brel,
                         const float* __restrict__ g0, const float* __restrict__ b0,
                         float* __restrict__ ws) {
    __shared__ float ps[512], pq[512];
    int tid = threadIdx.x, blk = blockIdx.x;
    if (blk < 40) {
        int f = blk * 64 + (tid & 63);
        int g = tid >> 6;   // 8 row-groups
        float s = 0.f, q = 0.f;
        for (int p = g; p < 125; p += 8) {
            s += ws[PSTAT + (long)p * 5000 + f];
            q += ws[PSTAT + (long)p * 5000 + 2500 + f];
        }
        ps[tid] = s; pq[tid] = q;
        __syncthreads();
        if (tid < 64) {
            float ss = 0.f, qq = 0.f;
#pragma unroll
            for (int k = 0; k < 8; k++) { ss += ps[tid + k * 64]; qq += pq[tid + k * 64]; }
            float mean = ss * (1.f / 1024.f);
            float var  = qq * (1.f / 1024.f) - mean * mean;
            float a = grel[f] * rsqrtf(var + EPS);
            ws[REL_A + f] = a;
            ws[REL_B + f] = brel[f] - mean * a;
        }
    } else if (tid == 0) {
        float s = 0.f, q = 0.f;
#pragma unroll
        for (int i = 0; i < 16; i++) { s += ws[EPART + 2 * i]; q += ws[EPART + 2 * i + 1]; }
        float mean = s * (1.f / 102400.f);
        float var  = q * (1.f / 102400.f) - mean * mean;
        float a = g0[0] * rsqrtf(var + EPS);
        ws[EAB]     = a;
        ws[EAB + 1] = b0[0] - mean * a;
    }
}

// K2: per-sample grouped conv; emits BN1 partials TRANSPOSED: bn1part[f][b] / [100+f][b]
__global__ void k_conv(const int* __restrict__ e1, const int* __restrict__ rel,
                       const float* __restrict__ emb_e, const float* __restrict__ emb_rel,
                       const float* __restrict__ ws, float* __restrict__ xout,
                       float* __restrict__ bn1part) {
    __shared__ float es[100];
    __shared__ float flt[2500];
    __shared__ float prs[600], prq[600];
    int b = blockIdx.x, tid = threadIdx.x;
    float a0 = ws[EAB], c0 = ws[EAB + 1];
    long ebase = (long)e1[b] * 100;
    for (int i = tid; i < 100; i += 256) es[i] = a0 * emb_e[ebase + i] + c0;
    long rbase = (long)rel[b] * 2500;
    for (int i = tid; i < 2500; i += 256) flt[i] = ws[REL_A + i] * emb_rel[rbase + i] + ws[REL_B + i];
    __syncthreads();
    for (int u = tid; u < 600; u += 256) {
        int f = u / 6, oi = u - f * 6;
        float er[5][10];
#pragma unroll
        for (int p = 0; p < 5; p++)
#pragma unroll
            for (int c = 0; c < 10; c++) er[p][c] = es[(oi + p) * 10 + c];
        float fw[25];
#pragma unroll
        for (int k = 0; k < 25; k++) fw[k] = flt[f * 25 + k];
        float* dst = xout + (long)b * 3600 + f * 36 + oi * 6;
        float s6 = 0.f, q6 = 0.f;
#pragma unroll
        for (int oj = 0; oj < 6; oj++) {
            float acc = 0.f;
#pragma unroll
            for (int p = 0; p < 5; p++)
#pragma unroll
                for (int q = 0; q < 5; q++) acc += er[p][oj + q] * fw[p * 5 + q];
            dst[oj] = acc;
            s6 += acc; q6 = fmaf(acc, acc, q6);
        }
        prs[u] = s6; prq[u] = q6;
    }
    __syncthreads();
    if (tid < 100) {
        float s = 0.f, q = 0.f;
#pragma unroll
        for (int k = 0; k < 6; k++) { s += prs[tid * 6 + k]; q += prq[tid * 6 + k]; }
        bn1part[(long)tid * 1024 + b]         = s;
        bn1part[(long)(100 + tid) * 1024 + b] = q;
    }
}

// K3: reduce BN1 partials (COALESCED rows) -> a1s/c1s
__global__ void k_bn1r(const float* __restrict__ bn1part, const float* __restrict__ g1,
                       const float* __restrict__ b1, float* __restrict__ ws) {
    __shared__ float ps[256], pq[256];
    int f = blockIdx.x, tid = threadIdx.x;
    float s = 0.f, q = 0.f;
    for (int b = tid; b < 1024; b += 256) {
        s += bn1part[(long)f * 1024 + b];
        q += bn1part[(long)(100 + f) * 1024 + b];
    }
    ps[tid] = s; pq[tid] = q;
    __syncthreads();
    for (int off = 128; off > 0; off >>= 1) {
        if (tid < off) { ps[tid] += ps[tid + off]; pq[tid] += pq[tid + off]; }
        __syncthreads();
    }
    if (tid == 0) {
        float mean = ps[0] * (1.f / 36864.f);
        float var  = pq[0] * (1.f / 36864.f) - mean * mean;
        float a = g1[f] * rsqrtf(var + EPS);
        ws[A1O + f] = a;
        ws[C1O + f] = b1[f] - mean * a;
    }
}

// K4: FC partials, COALESCED fc_w reads (round-9 form — break-terminated t-loop keeps
// registers low; xs reads broadcast across the wave's four 16-lane groups).
// grid (128, 4): 8 samples x 900-k chunk. part[(kc*100+j)*1024 + b]
__global__ void k_fc(const float* __restrict__ xbuf, const float* __restrict__ fc_w,
                     const float* __restrict__ ws, float* __restrict__ part) {
    __shared__ float a1s[100], c1s[100];
    __shared__ float xs[8][900];
    int tid = threadIdx.x;
    int sb = blockIdx.x, kc = blockIdx.y;
    if (tid < 100) { a1s[tid] = ws[A1O + tid]; c1s[tid] = ws[C1O + tid]; }
    __syncthreads();
    int b0s = sb * 8, k0 = kc * 900;
    for (int idx = tid; idx < 7200; idx += 256) {
        int s = idx / 900, k = idx - s * 900;
        int kg = k0 + k;
        int f = kg / 36;
        float v = xbuf[(long)(b0s + s) * 3600 + kg];
        v = a1s[f] * v + c1s[f];
        xs[s][k] = v > 0.f ? v : 0.f;
    }
    __syncthreads();
    int w = tid >> 6, l = tid & 63;
    int g = l >> 4, ks16 = l & 15;      // j-sub within group / k-lane
    for (int t = 0; t < 7; t++) {
        int grp = w + 4 * t;            // wave-uniform
        if (grp >= 25) break;
        int j = grp * 4 + g;
        const float* wrow = fc_w + (long)j * 3600 + k0;
        float acc[8];
#pragma unroll
        for (int s = 0; s < 8; s++) acc[s] = 0.f;
#pragma unroll
        for (int i = 0; i < 15; i++) {
            int kk = ks16 + i * 16;     // float4 index, 225 total
            if (kk < 225) {
                float4 w4 = *(const float4*)(wrow + kk * 4);
#pragma unroll
                for (int s = 0; s < 8; s++) {
                    float4 x4 = *(const float4*)(&xs[s][kk * 4]);
                    acc[s] += w4.x * x4.x + w4.y * x4.y + w4.z * x4.z + w4.w * x4.w;
                }
            }
        }
#pragma unroll
        for (int s = 0; s < 8; s++) {
            float v = acc[s];
            v += __shfl_xor(v, 1);
            v += __shfl_xor(v, 2);
            v += __shfl_xor(v, 4);
            v += __shfl_xor(v, 8);
            acc[s] = v;
        }
#pragma unroll
        for (int s = 0; s < 8; s++) {
            if (ks16 == s)
                part[((long)kc * 100 + j) * 1024 + b0s + s] = acc[s];
        }
    }
}

// K5: combine FC partials + fc_b, BN2 stats + apply + ReLU -> xhat bf16 [1024][128]
// part reads COALESCED (lanes along b).
__global__ void k_bn2x(const float* __restrict__ part, const float* __restrict__ fc_b,
                       const float* __restrict__ g2, const float* __restrict__ b2,
                       unsigned short* __restrict__ xhat) {
    int j = blockIdx.x, tid = threadIdx.x;
    if (j >= 100) {
        for (int t = 0; t < 4; t++) xhat[(long)(tid + t * 256) * 128 + j] = 0;
        return;
    }
    __shared__ float ps[256], pq[256];
    __shared__ float ab[2];
    float v[4];
    float s = 0.f, q = 0.f;
#pragma unroll
    for (int t = 0; t < 4; t++) {
        int b = tid + t * 256;
        float x = part[(long)j * 1024 + b] + part[(long)(100 + j) * 1024 + b]
                + part[(long)(200 + j) * 1024 + b] + part[(long)(300 + j) * 1024 + b]
                + fc_b[j];
        v[t] = x; s += x; q += x * x;
    }
    ps[tid] = s; pq[tid] = q;
    __syncthreads();
    for (int off = 128; off > 0; off >>= 1) {
        if (tid < off) { ps[tid] += ps[tid + off]; pq[tid] += pq[tid + off]; }
        __syncthreads();
    }
    if (tid == 0) {
        float mean = ps[0] * (1.f / 1024.f);
        float var  = pq[0] * (1.f / 1024.f) - mean * mean;
        float a = g2[j] * rsqrtf(var + EPS);
        ab[0] = a; ab[1] = b2[j] - mean * a;
    }
    __syncthreads();
    float a = ab[0], c = ab[1];
#pragma unroll
    for (int t = 0; t < 4; t++) {
        float x = a * v[t] + c;
        x = x > 0.f ? x : 0.f;
        xhat[(long)(tid + t * 256) * 128 + j] = f2bf(x);
    }
}

// K6: logits GEMM: N-tile 256, 2 blocks/CU, 1 KB contiguous NT row stores.
// Hardening vs r20 tripwire flake: post-store barrier is a FULL __syncthreads()
// (drains vmcnt(0) per chunk -> all NT stores globally visible before proceeding).
__global__ void __launch_bounds__(256, 2)
k_gemm(const unsigned short* __restrict__ xhat, const float* __restrict__ emb_e,
       const float* __restrict__ bias, float* __restrict__ out) {
    __shared__ __align__(16) unsigned short Es[256 * 128];  // 64 KB
    char* EsB = (char*)Es;
    int tid = threadIdx.x;
    int n0 = blockIdx.x * 256;

    {
        int r = tid;
        int g = n0 + r;
        unsigned int rowb = (unsigned)r * 256u;
        unsigned int sw = ((unsigned)r & 7u) << 4;
        ushort4 z; z.x = z.y = z.z = z.w = 0;
        if (g < NENT) {
            const float4* src = (const float4*)(emb_e + (long)g * 100);
#pragma unroll
            for (int i = 0; i < 25; i++) {
                float4 v = src[i];
                ushort4 h;
                h.x = f2bf(v.x); h.y = f2bf(v.y); h.z = f2bf(v.z); h.w = f2bf(v.w);
                *(ushort4*)(EsB + ((rowb + 8u * i) ^ sw)) = h;
            }
        } else {
#pragma unroll
            for (int i = 0; i < 25; i++) *(ushort4*)(EsB + ((rowb + 8u * i) ^ sw)) = z;
        }
#pragma unroll
        for (int zz = 0; zz < 7; zz++) *(ushort4*)(EsB + ((rowb + 200u + 8u * zz) ^ sw)) = z;
    }
    __syncthreads();

    int w = tid >> 6, l = tid & 63;
    int l15 = l & 15, l4 = l >> 4;

    bf16x8 Af[4][4];   // [ks][fe]
#pragma unroll
    for (int fe = 0; fe < 4; fe++) {
        unsigned int r = (unsigned)(w * 64 + fe * 16 + l15);
        unsigned int base = r * 256u + (unsigned)(l4 * 16);
        unsigned int sw = (r & 7u) << 4;
#pragma unroll
        for (int ks = 0; ks < 4; ks++)
            Af[ks][fe] = *(const bf16x8*)(EsB + ((base + (unsigned)(ks * 64)) ^ sw));
    }
    BARLK();   // Es dead as bf16 tile; reuse as float[64][256]

    int colg = n0 + l * 4;
    bool colv = colg < NENT;
    f32x4 bb = colv ? *(const f32x4*)(bias + colg) : f32x4{0.f, 0.f, 0.f, 0.f};

    int xrow = l15 * 128 + l4 * 8;

    bf16x8 Bp[4];
#pragma unroll
    for (int fx = 0; fx < 4; fx++)
        Bp[fx] = *(const bf16x8*)(xhat + (long)(fx * 2048 + xrow));

    for (int chunk = 0; chunk < 16; ++chunk) {
        int m0 = chunk * 64;
        f32x4 acc[4][4];
#pragma unroll
        for (int fe = 0; fe < 4; fe++)
#pragma unroll
            for (int fx = 0; fx < 4; fx++) acc[fe][fx] = f32x4{0.f, 0.f, 0.f, 0.f};

#pragma unroll
        for (int fe = 0; fe < 4; fe++)
#pragma unroll
            for (int fx = 0; fx < 4; fx++)
                acc[fe][fx] = __builtin_amdgcn_mfma_f32_16x16x32_bf16(Af[0][fe], Bp[fx], acc[fe][fx], 0, 0, 0);

#pragma unroll
        for (int ks = 1; ks < 4; ++ks) {
            bf16x8 Bf[4];
#pragma unroll
            for (int fx = 0; fx < 4; fx++)
                Bf[fx] = *(const bf16x8*)(xhat + (long)(m0 * 128 + fx * 2048 + ks * 32 + xrow));
#pragma unroll
            for (int fe = 0; fe < 4; fe++)
#pragma unroll
                for (int fx = 0; fx < 4; fx++)
                    acc[fe][fx] = __builtin_amdgcn_mfma_f32_16x16x32_bf16(Af[ks][fe], Bf[fx], acc[fe][fx], 0, 0, 0);
        }

        if (chunk < 15) {
            int m0n = (chunk + 1) * 64;
#pragma unroll
            for (int fx = 0; fx < 4; fx++)
                Bp[fx] = *(const bf16x8*)(xhat + (long)(m0n * 128 + fx * 2048 + xrow));
        }

#pragma unroll
        for (int fe = 0; fe < 4; fe++) {
            unsigned int s = (unsigned)(w * 16 + fe * 4 + l4);
#pragma unroll
            for (int fx = 0; fx < 4; fx++) {
                unsigned int row = (unsigned)(fx * 16 + l15);
                *(f32x4*)(EsB + row * 1024u + ((s ^ (row & 7u)) * 16u)) = acc[fe][fx];
            }
        }
        BARLK();

#pragma unroll
        for (int pass = 0; pass < 16; pass++) {
            unsigned int row = (unsigned)(pass * 4 + w);
            f32x4 v = *(f32x4*)(EsB + row * 1024u + ((((unsigned)l) ^ (row & 7u)) * 16u));
            f32x4 o;
#pragma unroll
            for (int k = 0; k < 4; k++) {
                float x = v[k] + bb[k];
                float e = __builtin_amdgcn_exp2f(x * -1.44269504f);
                o[k] = __builtin_amdgcn_rcpf(1.0f + e);
            }
            if (colv)
                __builtin_nontemporal_store(o, (f32x4*)(out + (long)(m0 + row) * NENT + colg));
        }
        __syncthreads();   // full drain (vmcnt) — hardening vs NT-store flake
    }
}

extern "C" void kernel_launch(void* const* d_in, const int* in_sizes, int n_in,
                              void* d_out, int out_size, void* d_ws, size_t ws_size,
                              hipStream_t stream) {
    const int*   e1      = (const int*)d_in[0];
    const int*   rel     = (const int*)d_in[1];
    const float* emb_e   = (const float*)d_in[2];
    const float* emb_rel = (const float*)d_in[3];
    const float* fc_w    = (const float*)d_in[4];
    const float* fc_b    = (const float*)d_in[5];
    const float* bias    = (const float*)d_in[6];
    const float* g0      = (const float*)d_in[7];
    const float* b0      = (const float*)d_in[8];
    const float* g1      = (const float*)d_in[9];
    const float* b1      = (const float*)d_in[10];
    const float* grel    = (const float*)d_in[11];
    const float* brel    = (const float*)d_in[12];
    const float* g2      = (const float*)d_in[13];
    const float* b2      = (const float*)d_in[14];
    float* ws  = (float*)d_ws;
    float* out = (float*)d_out;

    hipLaunchKernelGGL(k_stats1, dim3(141), dim3(256), 0, stream, rel, emb_rel, e1, emb_e, ws);
    hipLaunchKernelGGL(k_stats2, dim3(41), dim3(512), 0, stream, grel, brel, g0, b0, ws);
    hipLaunchKernelGGL(k_conv, dim3(1024), dim3(256), 0, stream, e1, rel, emb_e, emb_rel,
                       ws, ws + XBUF_OFF, ws + PART_OFF);
    hipLaunchKernelGGL(k_bn1r, dim3(100), dim3(256), 0, stream, ws + PART_OFF, g1, b1, ws);
    hipLaunchKernelGGL(k_fc, dim3(128, 4), dim3(256), 0, stream, ws + XBUF_OFF, fc_w, ws, ws + PART_OFF);
    hipLaunchKernelGGL(k_bn2x, dim3(128), dim3(256), 0, stream, ws + PART_OFF, fc_b, g2, b2,
                       (unsigned short*)(ws + XHAT_OFF));
    hipLaunchKernelGGL(k_gemm, dim3(391), dim3(256), 0, stream,
                       (const unsigned short*)(ws + XHAT_OFF), emb_e, bias, out);
}